// Round 1
// baseline (524.240 us; speedup 1.0000x reference)
//
#include <hip/hip_runtime.h>
#include <math.h>

#define D 65536
#define NT 256
#define NG 256
#define NL 1024
#define NS 1280          // NG + NL
#define CT 32            // column tiles in kA
#define TILE_W 2048      // columns per tile (32 per lane)
#define RG 40            // row groups (32 rows each)
#define ROWS_PER_BLK 32
#define KC_SPLIT 4       // blocks per teacher row

typedef float vfloat4 __attribute__((ext_vector_type(4)));

// ws layout (floats):
// [0, D)                     : Sxs (column sums of u_s), memset to 0
// [D, D + CT*NS*2)           : stats float2 [CT][NS]  (m, Z partials)
// [D + CT*NS*2, +NT*KC_SPLIT*4) : teacher tuples float4 (m, Z, A, Dg)

__global__ __launch_bounds__(256) void kA(const float* __restrict__ sg,
                                          const float* __restrict__ sl,
                                          const float* __restrict__ tempS,
                                          float* __restrict__ Sxs,
                                          float2* __restrict__ stats) {
    const int tid  = threadIdx.x;
    const int lane = tid & 63;
    const int w    = tid >> 6;           // wave 0..3
    const int ct   = blockIdx.x;         // 0..31
    const int gy   = blockIdx.y;         // 0..39
    const int c0   = ct * TILE_W;
    const float invTs = 1.0f / tempS[0];

    __shared__ float lds_sx[4][TILE_W];  // 32 KB

    float sx[32];
    #pragma unroll
    for (int j = 0; j < 32; ++j) sx[j] = 0.0f;

    for (int i = 0; i < 8; ++i) {
        const int r = gy * ROWS_PER_BLK + i * 4 + w;       // wave-uniform row
        const bool is_local = (r >= NG);
        const float* row = is_local ? (sl + (size_t)(r - NG) * D)
                                    : (sg + (size_t)r * D);
        float u[32];
        #pragma unroll
        for (int ch = 0; ch < 8; ++ch) {
            const vfloat4* p = (const vfloat4*)(row + c0 + ch * 256) + lane;
            vfloat4 v = is_local ? __builtin_nontemporal_load(p) : *p;
            u[ch*4+0] = v.x * invTs;
            u[ch*4+1] = v.y * invTs;
            u[ch*4+2] = v.z * invTs;
            u[ch*4+3] = v.w * invTs;
        }
        // wave max
        float m = u[0];
        #pragma unroll
        for (int j = 1; j < 32; ++j) m = fmaxf(m, u[j]);
        #pragma unroll
        for (int off = 32; off; off >>= 1) m = fmaxf(m, __shfl_xor(m, off, 64));
        // wave sumexp
        float z = 0.0f;
        #pragma unroll
        for (int j = 0; j < 32; ++j) z += __expf(u[j] - m);
        #pragma unroll
        for (int off = 32; off; off >>= 1) z += __shfl_xor(z, off, 64);
        if (lane == 0) stats[ct * NS + r] = make_float2(m, z);
        // column-sum accumulation (scaled values)
        #pragma unroll
        for (int j = 0; j < 32; ++j) sx[j] += u[j];
    }

    // combine per-wave column sums via LDS, then one atomic per column
    #pragma unroll
    for (int ch = 0; ch < 8; ++ch) {
        #pragma unroll
        for (int j = 0; j < 4; ++j)
            lds_sx[w][ch*256 + lane*4 + j] = sx[ch*4 + j];
    }
    __syncthreads();
    #pragma unroll
    for (int k = 0; k < 8; ++k) {
        const int idx = tid * 8 + k;
        const float v = lds_sx[0][idx] + lds_sx[1][idx] + lds_sx[2][idx] + lds_sx[3][idx];
        atomicAdd(&Sxs[c0 + idx], v);
    }
}

__global__ __launch_bounds__(256) void kC(const float* __restrict__ tch,
                                          const float* __restrict__ sg,
                                          const float* __restrict__ center,
                                          const float* __restrict__ Sxs,
                                          const float* __restrict__ tempS,
                                          const float* __restrict__ tempT,
                                          float4* __restrict__ tup) {
    const int t   = blockIdx.x >> 2;     // teacher row
    const int q   = blockIdx.x & 3;      // column quarter
    const int tid = threadIdx.x;
    const float invTt = 1.0f / tempT[0];
    const float invTs = 1.0f / tempS[0];

    const float4* xt = (const float4*)(tch + (size_t)t * D);
    const float4* xg = (const float4*)(sg  + (size_t)t * D);
    const float4* c4 = (const float4*)center;
    const float4* s4 = (const float4*)Sxs;

    float m = -INFINITY, Z = 0.0f, A = 0.0f, Dg = 0.0f;
    const int base = q * 4096;           // float4 index base
    for (int it = 0; it < 16; ++it) {
        const int idx = base + it * 256 + tid;
        const float4 x = xt[idx];
        const float4 c = c4[idx];
        const float4 g = xg[idx];
        const float4 s = s4[idx];
        const float ys[4] = {(x.x-c.x)*invTt, (x.y-c.y)*invTt, (x.z-c.z)*invTt, (x.w-c.w)*invTt};
        const float gs[4] = {g.x*invTs, g.y*invTs, g.z*invTs, g.w*invTs};
        const float ss[4] = {s.x, s.y, s.z, s.w};
        #pragma unroll
        for (int j = 0; j < 4; ++j) {
            const float y  = ys[j];
            const float mn = fmaxf(m, y);
            const float sc = __expf(m - mn);   // 1 when max unchanged
            const float f  = __expf(y - mn);
            Z  = Z  * sc + f;
            A  = A  * sc + f * ss[j];
            Dg = Dg * sc + f * gs[j];
            m  = mn;
        }
    }
    // butterfly tuple merge across the wave
    #pragma unroll
    for (int off = 32; off; off >>= 1) {
        const float m2 = __shfl_xor(m,  off, 64);
        const float Z2 = __shfl_xor(Z,  off, 64);
        const float A2 = __shfl_xor(A,  off, 64);
        const float G2 = __shfl_xor(Dg, off, 64);
        const float mn = fmaxf(m, m2);
        const float s1 = __expf(m  - mn);
        const float s2 = __expf(m2 - mn);
        Z  = Z  * s1 + Z2 * s2;
        A  = A  * s1 + A2 * s2;
        Dg = Dg * s1 + G2 * s2;
        m  = mn;
    }
    __shared__ float4 lds[4];
    const int w = tid >> 6, lane = tid & 63;
    if (lane == 0) lds[w] = make_float4(m, Z, A, Dg);
    __syncthreads();
    if (tid == 0) {
        float4 r = lds[0];
        for (int k = 1; k < 4; ++k) {
            const float4 p = lds[k];
            const float mn = fmaxf(r.x, p.x);
            const float s1 = __expf(r.x - mn);
            const float s2 = __expf(p.x - mn);
            r = make_float4(mn, r.y*s1 + p.y*s2, r.z*s1 + p.z*s2, r.w*s1 + p.w*s2);
        }
        tup[blockIdx.x] = r;
    }
}

__global__ __launch_bounds__(256) void kD(const float2* __restrict__ stats,
                                          const float4* __restrict__ tup,
                                          float* __restrict__ out) {
    const int tid = threadIdx.x;
    float accC = 0.0f, accCg = 0.0f;
    for (int r = tid; r < NS; r += 256) {
        float m = -INFINITY, Z = 0.0f;
        for (int ct = 0; ct < CT; ++ct) {
            const float2 p = stats[ct * NS + r];
            const float mn = fmaxf(m, p.x);
            Z = Z * __expf(m - mn) + p.y * __expf(p.x - mn);
            m = mn;
        }
        const float l = m + logf(Z);
        accC += l;
        if (r < NG) accCg += l;
    }
    float termS = 0.0f;
    if (tid < NT) {
        float4 r = tup[KC_SPLIT * tid];
        for (int k = 1; k < KC_SPLIT; ++k) {
            const float4 p = tup[KC_SPLIT * tid + k];
            const float mn = fmaxf(r.x, p.x);
            const float s1 = __expf(r.x - mn);
            const float s2 = __expf(p.x - mn);
            r = make_float4(mn, r.y*s1 + p.y*s2, r.z*s1 + p.z*s2, r.w*s1 + p.w*s2);
        }
        termS = (r.z - r.w) / r.y;   // (A - Dg)/Z
    }
    // block reduce the three sums
    #pragma unroll
    for (int off = 32; off; off >>= 1) {
        accC  += __shfl_xor(accC,  off, 64);
        accCg += __shfl_xor(accCg, off, 64);
        termS += __shfl_xor(termS, off, 64);
    }
    __shared__ float l1[4], l2[4], l3[4];
    const int w = tid >> 6, lane = tid & 63;
    if (lane == 0) { l1[w] = accC; l2[w] = accCg; l3[w] = termS; }
    __syncthreads();
    if (tid == 0) {
        float C = 0.0f, Cg = 0.0f, S = 0.0f;
        for (int k = 0; k < 4; ++k) { C += l1[k]; Cg += l2[k]; S += l3[k]; }
        // total = 256*C - C_g - sum_t (A_t - Dg_t)/Z_t ; n_loss_terms = 256*1280-256
        out[0] = (256.0f * C - Cg - S) * (1.0f / 327424.0f);
    }
}

extern "C" void kernel_launch(void* const* d_in, const int* in_sizes, int n_in,
                              void* d_out, int out_size, void* d_ws, size_t ws_size,
                              hipStream_t stream) {
    const float* sg     = (const float*)d_in[0];   // out_student_global [256, D]
    const float* sl     = (const float*)d_in[1];   // out_student_local  [1024, D]
    const float* tch    = (const float*)d_in[2];   // out_teacher        [256, D]
    const float* center = (const float*)d_in[3];   // [1, D]
    const float* tempS  = (const float*)d_in[4];
    const float* tempT  = (const float*)d_in[5];
    // d_in[6] = cent_rate_m (unused by the reference output)

    float* ws = (float*)d_ws;
    float*  Sxs   = ws;                                  // D floats
    float2* stats = (float2*)(ws + D);                   // CT*NS float2
    float4* tup   = (float4*)(ws + D + CT * NS * 2);     // NT*KC_SPLIT float4

    hipMemsetAsync(Sxs, 0, D * sizeof(float), stream);
    kA<<<dim3(CT, RG), 256, 0, stream>>>(sg, sl, tempS, Sxs, stats);
    kC<<<NT * KC_SPLIT, 256, 0, stream>>>(tch, sg, center, Sxs, tempS, tempT, tup);
    kD<<<1, 256, 0, stream>>>(stats, tup, (float*)d_out);
}

// Round 2
// 500.577 us; speedup vs baseline: 1.0473x; 1.0473x over previous
//
#include <hip/hip_runtime.h>
#include <math.h>

#define D 65536
#define NT 256
#define NG 256
#define NL 1024
#define NS 1280          // NG + NL
#define CT 32            // column tiles in kA
#define TILE_W 2048      // columns per tile (32 per lane)
#define RG 40            // row groups (32 rows each)
#define ROWS_PER_BLK 32
#define KC_SPLIT 8       // blocks per teacher row

typedef float vfloat4 __attribute__((ext_vector_type(4)));

// ws layout (floats):
// [0, D)                          : Sxs (column sums of u_s)
// [D, +CT*NS*2)                   : stats float2 [CT][NS]  (m, Z partials)
// [.., +NT*KC_SPLIT*4)            : teacher tuples float4 (m, Z, A, Dg)
// [.., +RG*D)                     : per-rowgroup column-sum partials (non-atomic path)

__device__ __forceinline__ float max4(vfloat4 v) {
    return fmaxf(fmaxf(v.x, v.y), fmaxf(v.z, v.w));
}

__global__ __launch_bounds__(256) void kA(const float* __restrict__ sg,
                                          const float* __restrict__ sl,
                                          const float* __restrict__ tempS,
                                          float* __restrict__ Sxs,
                                          float* __restrict__ partial,
                                          float2* __restrict__ stats,
                                          int use_atomic) {
    const int tid  = threadIdx.x;
    const int lane = tid & 63;
    const int w    = tid >> 6;           // wave 0..3
    const int ct   = blockIdx.x;         // 0..31
    const int gy   = blockIdx.y;         // 0..39
    const int c0   = ct * TILE_W;
    const float invTs = 1.0f / tempS[0];

    __shared__ float lds_sx[4][TILE_W];  // 32 KB

    vfloat4 sx[8];
    #pragma unroll
    for (int j = 0; j < 8; ++j) sx[j] = (vfloat4)0.0f;

    for (int i = 0; i < 8; ++i) {
        const int r = gy * ROWS_PER_BLK + i * 4 + w;       // wave-uniform row
        const float* row = (r >= NG) ? (sl + (size_t)(r - NG) * D)
                                     : (sg + (size_t)r * D);
        const vfloat4* p = (const vfloat4*)(row + c0) + lane;

        float m = -INFINITY, z = 0.0f;
        #pragma unroll
        for (int ch = 0; ch < 8; ++ch) {
            vfloat4 v = p[ch * 64];          // 1 KB stride per chunk
            vfloat4 u = v * invTs;
            sx[ch] += u;
            const float mn = fmaxf(m, max4(u));
            const float f0 = __expf(u.x - mn);
            const float f1 = __expf(u.y - mn);
            const float f2 = __expf(u.z - mn);
            const float f3 = __expf(u.w - mn);
            z = z * __expf(m - mn) + ((f0 + f1) + (f2 + f3));
            m = mn;
        }
        // merge (m,z) across the wave
        #pragma unroll
        for (int off = 32; off; off >>= 1) {
            const float m2 = __shfl_xor(m, off, 64);
            const float z2 = __shfl_xor(z, off, 64);
            const float mn = fmaxf(m, m2);
            z = z * __expf(m - mn) + z2 * __expf(m2 - mn);
            m = mn;
        }
        if (lane == 0) stats[ct * NS + r] = make_float2(m, z);
    }

    // combine per-wave column sums via LDS
    #pragma unroll
    for (int ch = 0; ch < 8; ++ch)
        ((vfloat4*)&lds_sx[w][ch * 256])[lane] = sx[ch];
    __syncthreads();

    #pragma unroll
    for (int k = 0; k < 2; ++k) {
        const int i4 = k * 256 + tid;        // float4 index within tile (512 total)
        vfloat4 v = ((vfloat4*)lds_sx[0])[i4] + ((vfloat4*)lds_sx[1])[i4]
                  + ((vfloat4*)lds_sx[2])[i4] + ((vfloat4*)lds_sx[3])[i4];
        if (use_atomic) {
            const int c = c0 + i4 * 4;
            atomicAdd(&Sxs[c + 0], v.x);
            atomicAdd(&Sxs[c + 1], v.y);
            atomicAdd(&Sxs[c + 2], v.z);
            atomicAdd(&Sxs[c + 3], v.w);
        } else {
            ((vfloat4*)(partial + (size_t)gy * D + c0))[i4] = v;
        }
    }
}

__global__ __launch_bounds__(256) void kB(const float* __restrict__ partial,
                                          float* __restrict__ Sxs) {
    const int col = blockIdx.x * 256 + threadIdx.x;
    float s = 0.0f;
    #pragma unroll 8
    for (int g = 0; g < RG; ++g) s += partial[(size_t)g * D + col];
    Sxs[col] = s;
}

__global__ __launch_bounds__(256) void kC(const float* __restrict__ tch,
                                          const float* __restrict__ sg,
                                          const float* __restrict__ center,
                                          const float* __restrict__ Sxs,
                                          const float* __restrict__ tempS,
                                          const float* __restrict__ tempT,
                                          float4* __restrict__ tup) {
    const int t   = blockIdx.x / KC_SPLIT;   // teacher row
    const int q   = blockIdx.x % KC_SPLIT;   // column slice
    const int tid = threadIdx.x;
    const float invTt = 1.0f / tempT[0];
    const float invTs = 1.0f / tempS[0];

    const float4* xt = (const float4*)(tch + (size_t)t * D);
    const float4* xg = (const float4*)(sg  + (size_t)t * D);
    const float4* c4 = (const float4*)center;
    const float4* s4 = (const float4*)Sxs;

    float m = -INFINITY, Z = 0.0f, A = 0.0f, Dg = 0.0f;
    const int base = q * (D / 4 / KC_SPLIT);           // 2048 float4 per slice
    for (int it = 0; it < (D / 4 / KC_SPLIT) / 256; ++it) {
        const int idx = base + it * 256 + tid;
        const float4 x = xt[idx];
        const float4 c = c4[idx];
        const float4 g = xg[idx];
        const float4 s = s4[idx];
        const float y0 = (x.x - c.x) * invTt, y1 = (x.y - c.y) * invTt;
        const float y2 = (x.z - c.z) * invTt, y3 = (x.w - c.w) * invTt;
        const float mn = fmaxf(m, fmaxf(fmaxf(y0, y1), fmaxf(y2, y3)));
        const float sc = __expf(m - mn);
        const float f0 = __expf(y0 - mn), f1 = __expf(y1 - mn);
        const float f2 = __expf(y2 - mn), f3 = __expf(y3 - mn);
        Z  = Z  * sc + ((f0 + f1) + (f2 + f3));
        A  = A  * sc + ((f0 * s.x + f1 * s.y) + (f2 * s.z + f3 * s.w));
        Dg = Dg * sc + ((f0 * g.x + f1 * g.y) + (f2 * g.z + f3 * g.w)) * invTs;
        m  = mn;
    }
    // butterfly tuple merge across the wave
    #pragma unroll
    for (int off = 32; off; off >>= 1) {
        const float m2 = __shfl_xor(m,  off, 64);
        const float Z2 = __shfl_xor(Z,  off, 64);
        const float A2 = __shfl_xor(A,  off, 64);
        const float G2 = __shfl_xor(Dg, off, 64);
        const float mn = fmaxf(m, m2);
        const float s1 = __expf(m  - mn);
        const float s2 = __expf(m2 - mn);
        Z  = Z  * s1 + Z2 * s2;
        A  = A  * s1 + A2 * s2;
        Dg = Dg * s1 + G2 * s2;
        m  = mn;
    }
    __shared__ float4 lds[4];
    const int w = tid >> 6, lane = tid & 63;
    if (lane == 0) lds[w] = make_float4(m, Z, A, Dg);
    __syncthreads();
    if (tid == 0) {
        float4 r = lds[0];
        for (int k = 1; k < 4; ++k) {
            const float4 p = lds[k];
            const float mn = fmaxf(r.x, p.x);
            const float s1 = __expf(r.x - mn);
            const float s2 = __expf(p.x - mn);
            r = make_float4(mn, r.y*s1 + p.y*s2, r.z*s1 + p.z*s2, r.w*s1 + p.w*s2);
        }
        tup[blockIdx.x] = r;
    }
}

__global__ __launch_bounds__(256) void kD(const float2* __restrict__ stats,
                                          const float4* __restrict__ tup,
                                          float* __restrict__ out) {
    const int tid = threadIdx.x;
    float accC = 0.0f, accCg = 0.0f;
    for (int r = tid; r < NS; r += 256) {
        float m = -INFINITY, Z = 0.0f;
        for (int ct = 0; ct < CT; ++ct) {
            const float2 p = stats[ct * NS + r];
            const float mn = fmaxf(m, p.x);
            Z = Z * __expf(m - mn) + p.y * __expf(p.x - mn);
            m = mn;
        }
        const float l = m + logf(Z);
        accC += l;
        if (r < NG) accCg += l;
    }
    float termS = 0.0f;
    if (tid < NT) {
        float4 r = tup[KC_SPLIT * tid];
        for (int k = 1; k < KC_SPLIT; ++k) {
            const float4 p = tup[KC_SPLIT * tid + k];
            const float mn = fmaxf(r.x, p.x);
            const float s1 = __expf(r.x - mn);
            const float s2 = __expf(p.x - mn);
            r = make_float4(mn, r.y*s1 + p.y*s2, r.z*s1 + p.z*s2, r.w*s1 + p.w*s2);
        }
        termS = (r.z - r.w) / r.y;   // (A - Dg)/Z
    }
    // block reduce the three sums
    #pragma unroll
    for (int off = 32; off; off >>= 1) {
        accC  += __shfl_xor(accC,  off, 64);
        accCg += __shfl_xor(accCg, off, 64);
        termS += __shfl_xor(termS, off, 64);
    }
    __shared__ float l1[4], l2[4], l3[4];
    const int w = tid >> 6, lane = tid & 63;
    if (lane == 0) { l1[w] = accC; l2[w] = accCg; l3[w] = termS; }
    __syncthreads();
    if (tid == 0) {
        float C = 0.0f, Cg = 0.0f, S = 0.0f;
        for (int k = 0; k < 4; ++k) { C += l1[k]; Cg += l2[k]; S += l3[k]; }
        // total = 256*C - C_g - sum_t (A_t - Dg_t)/Z_t ; n_loss_terms = 256*1280-256
        out[0] = (256.0f * C - Cg - S) * (1.0f / 327424.0f);
    }
}

extern "C" void kernel_launch(void* const* d_in, const int* in_sizes, int n_in,
                              void* d_out, int out_size, void* d_ws, size_t ws_size,
                              hipStream_t stream) {
    const float* sg     = (const float*)d_in[0];   // out_student_global [256, D]
    const float* sl     = (const float*)d_in[1];   // out_student_local  [1024, D]
    const float* tch    = (const float*)d_in[2];   // out_teacher        [256, D]
    const float* center = (const float*)d_in[3];   // [1, D]
    const float* tempS  = (const float*)d_in[4];
    const float* tempT  = (const float*)d_in[5];
    // d_in[6] = cent_rate_m (unused by the reference output)

    float* ws = (float*)d_ws;
    float*  Sxs     = ws;                                         // D floats
    float2* stats   = (float2*)(ws + D);                          // CT*NS float2
    float4* tup     = (float4*)(ws + D + CT * NS * 2);            // NT*KC_SPLIT float4
    float*  partial = ws + D + CT * NS * 2 + NT * KC_SPLIT * 4;   // RG*D floats

    const size_t needed = (size_t)(D + CT * NS * 2 + NT * KC_SPLIT * 4 + RG * D) * sizeof(float);
    const int use_atomic = (ws_size < needed) ? 1 : 0;

    if (use_atomic)
        hipMemsetAsync(Sxs, 0, D * sizeof(float), stream);
    kA<<<dim3(CT, RG), 256, 0, stream>>>(sg, sl, tempS, Sxs, partial, stats, use_atomic);
    if (!use_atomic)
        kB<<<D / 256, 256, 0, stream>>>(partial, Sxs);
    kC<<<NT * KC_SPLIT, 256, 0, stream>>>(tch, sg, center, Sxs, tempS, tempT, tup);
    kD<<<1, 256, 0, stream>>>(stats, tup, (float*)d_out);
}

// Round 4
// 478.490 us; speedup vs baseline: 1.0956x; 1.0462x over previous
//
#include <hip/hip_runtime.h>
#include <math.h>

#define D 65536
#define NT 256
#define NG 256
#define NL 1024
#define NS 1280          // NG + NL
#define CT 32            // column tiles in kA
#define TILE_W 2048      // columns per tile (32 per lane)
#define RG 40            // row groups (32 rows each)
#define KC_SPLIT 8       // blocks per teacher row

typedef float vfloat4 __attribute__((ext_vector_type(4)));

// ws layout (floats):
// [0, D)                          : Sxs (column sums of u_s)
// [D, +NS*CT*2)                   : stats float2 [row][tile]  (m, Z partials) -- TRANSPOSED
// [.., +NT*KC_SPLIT*4)            : teacher tuples float4 (m, Z, A, Dg)
// [.., +RG*D)                     : per-rowgroup column-sum partials (non-atomic path)

__device__ __forceinline__ float max4(vfloat4 v) {
    return fmaxf(fmaxf(v.x, v.y), fmaxf(v.z, v.w));
}

__global__ __launch_bounds__(256) void kA(const float* __restrict__ sg,
                                          const float* __restrict__ sl,
                                          const float* __restrict__ tempS,
                                          float* __restrict__ Sxs,
                                          float* __restrict__ partial,
                                          float2* __restrict__ stats,
                                          int use_atomic) {
    const int tid  = threadIdx.x;
    const int lane = tid & 63;
    const int w    = tid >> 6;           // wave 0..3
    const int ct   = blockIdx.x;         // 0..31
    const int gy   = blockIdx.y;         // 0..39
    const int c0   = ct * TILE_W;
    const float invTs = 1.0f / tempS[0];
    const bool is_local = (gy >= 8);     // 32-row groups align with the 256 boundary

    __shared__ float lds_sx[4][TILE_W];  // 32 KB

    vfloat4 sx[8];
    #pragma unroll
    for (int j = 0; j < 8; ++j) sx[j] = (vfloat4)0.0f;

    for (int i = 0; i < 4; ++i) {
        const int rA = gy * 32 + i * 8 + w;       // wave-uniform rows
        const int rB = rA + 4;
        const float* rowA = is_local ? (sl + (size_t)(rA - NG) * D) : (sg + (size_t)rA * D);
        const float* rowB = is_local ? (sl + (size_t)(rB - NG) * D) : (sg + (size_t)rB * D);
        const vfloat4* pA = (const vfloat4*)(rowA + c0) + lane;
        const vfloat4* pB = (const vfloat4*)(rowB + c0) + lane;

        float mA = -INFINITY, zA = 0.0f;
        float mB = -INFINITY, zB = 0.0f;
        #pragma unroll
        for (int h = 0; h < 2; ++h) {
            vfloat4 a[4], b[4];
            #pragma unroll
            for (int j = 0; j < 4; ++j) {
                const vfloat4* qa = pA + (h * 4 + j) * 64;
                const vfloat4* qb = pB + (h * 4 + j) * 64;
                a[j] = is_local ? __builtin_nontemporal_load(qa) : *qa;
                b[j] = is_local ? __builtin_nontemporal_load(qb) : *qb;
            }
            #pragma unroll
            for (int j = 0; j < 4; ++j) {
                const vfloat4 ua = a[j] * invTs;
                const vfloat4 ub = b[j] * invTs;
                sx[h * 4 + j] += ua + ub;
                // two independent online chains (ILP)
                const float mnA = fmaxf(mA, max4(ua));
                const float mnB = fmaxf(mB, max4(ub));
                const float fa = (__expf(ua.x - mnA) + __expf(ua.y - mnA))
                               + (__expf(ua.z - mnA) + __expf(ua.w - mnA));
                const float fb = (__expf(ub.x - mnB) + __expf(ub.y - mnB))
                               + (__expf(ub.z - mnB) + __expf(ub.w - mnB));
                zA = zA * __expf(mA - mnA) + fa;
                zB = zB * __expf(mB - mnB) + fb;
                mA = mnA;
                mB = mnB;
            }
        }
        // merge (m,z) pairs across the wave (both rows interleaved)
        #pragma unroll
        for (int off = 32; off; off >>= 1) {
            const float mA2 = __shfl_xor(mA, off, 64);
            const float zA2 = __shfl_xor(zA, off, 64);
            const float mB2 = __shfl_xor(mB, off, 64);
            const float zB2 = __shfl_xor(zB, off, 64);
            const float mnA = fmaxf(mA, mA2);
            const float mnB = fmaxf(mB, mB2);
            zA = zA * __expf(mA - mnA) + zA2 * __expf(mA2 - mnA);
            zB = zB * __expf(mB - mnB) + zB2 * __expf(mB2 - mnB);
            mA = mnA;
            mB = mnB;
        }
        if (lane == 0) {
            stats[(size_t)rA * CT + ct] = make_float2(mA, zA);
            stats[(size_t)rB * CT + ct] = make_float2(mB, zB);
        }
    }

    // combine per-wave column sums via LDS
    #pragma unroll
    for (int ch = 0; ch < 8; ++ch)
        ((vfloat4*)&lds_sx[w][ch * 256])[lane] = sx[ch];
    __syncthreads();

    #pragma unroll
    for (int k = 0; k < 2; ++k) {
        const int i4 = k * 256 + tid;        // float4 index within tile (512 total)
        vfloat4 v = ((vfloat4*)lds_sx[0])[i4] + ((vfloat4*)lds_sx[1])[i4]
                  + ((vfloat4*)lds_sx[2])[i4] + ((vfloat4*)lds_sx[3])[i4];
        if (use_atomic) {
            const int c = c0 + i4 * 4;
            atomicAdd(&Sxs[c + 0], v.x);
            atomicAdd(&Sxs[c + 1], v.y);
            atomicAdd(&Sxs[c + 2], v.z);
            atomicAdd(&Sxs[c + 3], v.w);
        } else {
            ((vfloat4*)(partial + (size_t)gy * D + c0))[i4] = v;
        }
    }
}

__global__ __launch_bounds__(256) void kB(const float* __restrict__ partial,
                                          float* __restrict__ Sxs) {
    const int col = blockIdx.x * 256 + threadIdx.x;
    float s = 0.0f;
    #pragma unroll 8
    for (int g = 0; g < RG; ++g) s += partial[(size_t)g * D + col];
    Sxs[col] = s;
}

__global__ __launch_bounds__(256) void kC(const float* __restrict__ tch,
                                          const float* __restrict__ sg,
                                          const float* __restrict__ center,
                                          const float* __restrict__ Sxs,
                                          const float* __restrict__ tempS,
                                          const float* __restrict__ tempT,
                                          float4* __restrict__ tup) {
    const int t   = blockIdx.x >> 3;     // teacher row
    const int q   = blockIdx.x & 7;      // column slice
    const int tid = threadIdx.x;
    const float invTt = 1.0f / tempT[0];
    const float invTs = 1.0f / tempS[0];

    const vfloat4* xt = (const vfloat4*)(tch + (size_t)t * D);
    const vfloat4* xg = (const vfloat4*)(sg  + (size_t)t * D);
    const float4*  c4 = (const float4*)center;
    const float4*  s4 = (const float4*)Sxs;

    float m = -INFINITY, Z = 0.0f, A = 0.0f, Dg = 0.0f;
    const int base = q * (D / 4 / KC_SPLIT);           // 2048 float4 per slice
    #pragma unroll 2
    for (int it = 0; it < (D / 4 / KC_SPLIT) / 256; ++it) {
        const int idx = base + it * 256 + tid;
        const vfloat4 x = __builtin_nontemporal_load(xt + idx);
        const vfloat4 g = __builtin_nontemporal_load(xg + idx);
        const float4  c = c4[idx];
        const float4  s = s4[idx];
        const float y0 = (x.x - c.x) * invTt, y1 = (x.y - c.y) * invTt;
        const float y2 = (x.z - c.z) * invTt, y3 = (x.w - c.w) * invTt;
        const float mn = fmaxf(m, fmaxf(fmaxf(y0, y1), fmaxf(y2, y3)));
        const float sc = __expf(m - mn);
        const float f0 = __expf(y0 - mn), f1 = __expf(y1 - mn);
        const float f2 = __expf(y2 - mn), f3 = __expf(y3 - mn);
        Z  = Z  * sc + ((f0 + f1) + (f2 + f3));
        A  = A  * sc + ((f0 * s.x + f1 * s.y) + (f2 * s.z + f3 * s.w));
        Dg = Dg * sc + ((f0 * g.x + f1 * g.y) + (f2 * g.z + f3 * g.w)) * invTs;
        m  = mn;
    }
    // butterfly tuple merge across the wave
    #pragma unroll
    for (int off = 32; off; off >>= 1) {
        const float m2 = __shfl_xor(m,  off, 64);
        const float Z2 = __shfl_xor(Z,  off, 64);
        const float A2 = __shfl_xor(A,  off, 64);
        const float G2 = __shfl_xor(Dg, off, 64);
        const float mn = fmaxf(m, m2);
        const float s1 = __expf(m  - mn);
        const float s2 = __expf(m2 - mn);
        Z  = Z  * s1 + Z2 * s2;
        A  = A  * s1 + A2 * s2;
        Dg = Dg * s1 + G2 * s2;
        m  = mn;
    }
    __shared__ float4 lds[4];
    const int w = tid >> 6, lane = tid & 63;
    if (lane == 0) lds[w] = make_float4(m, Z, A, Dg);
    __syncthreads();
    if (tid == 0) {
        float4 r = lds[0];
        for (int k = 1; k < 4; ++k) {
            const float4 p = lds[k];
            const float mn = fmaxf(r.x, p.x);
            const float s1 = __expf(r.x - mn);
            const float s2 = __expf(p.x - mn);
            r = make_float4(mn, r.y*s1 + p.y*s2, r.z*s1 + p.z*s2, r.w*s1 + p.w*s2);
        }
        tup[blockIdx.x] = r;
    }
}

__device__ __forceinline__ float2 merge2(float2 a, float2 b) {
    const float mn = fmaxf(a.x, b.x);
    return make_float2(mn, a.y * __expf(a.x - mn) + b.y * __expf(b.x - mn));
}

__global__ __launch_bounds__(256) void kD(const float2* __restrict__ stats,
                                          const float4* __restrict__ tup,
                                          float* __restrict__ out) {
    const int tid = threadIdx.x;
    float accC = 0.0f, accCg = 0.0f;
    for (int r = tid; r < NS; r += 256) {
        // CT=32 float2 per row = 16 float4 (round-3 bug: only read 8)
        const float4* sp = (const float4*)(stats + (size_t)r * CT);
        float4 v[16];
        #pragma unroll
        for (int k = 0; k < 16; ++k) v[k] = sp[k];   // independent loads
        float2 p[16];
        #pragma unroll
        for (int k = 0; k < 16; ++k)
            p[k] = merge2(make_float2(v[k].x, v[k].y), make_float2(v[k].z, v[k].w));
        #pragma unroll
        for (int step = 8; step; step >>= 1)
            #pragma unroll
            for (int k = 0; k < step; ++k) p[k] = merge2(p[k], p[k + step]);
        const float l = p[0].x + logf(p[0].y);
        accC += l;
        if (r < NG) accCg += l;
    }
    float termS = 0.0f;
    if (tid < NT) {
        float4 r = tup[KC_SPLIT * tid];
        for (int k = 1; k < KC_SPLIT; ++k) {
            const float4 pp = tup[KC_SPLIT * tid + k];
            const float mn = fmaxf(r.x, pp.x);
            const float s1 = __expf(r.x - mn);
            const float s2 = __expf(pp.x - mn);
            r = make_float4(mn, r.y*s1 + pp.y*s2, r.z*s1 + pp.z*s2, r.w*s1 + pp.w*s2);
        }
        termS = (r.z - r.w) / r.y;   // (A - Dg)/Z
    }
    // block reduce the three sums
    #pragma unroll
    for (int off = 32; off; off >>= 1) {
        accC  += __shfl_xor(accC,  off, 64);
        accCg += __shfl_xor(accCg, off, 64);
        termS += __shfl_xor(termS, off, 64);
    }
    __shared__ float l1[4], l2[4], l3[4];
    const int w = tid >> 6, lane = tid & 63;
    if (lane == 0) { l1[w] = accC; l2[w] = accCg; l3[w] = termS; }
    __syncthreads();
    if (tid == 0) {
        float C = 0.0f, Cg = 0.0f, S = 0.0f;
        for (int k = 0; k < 4; ++k) { C += l1[k]; Cg += l2[k]; S += l3[k]; }
        // total = 256*C - C_g - sum_t (A_t - Dg_t)/Z_t ; n_loss_terms = 256*1280-256
        out[0] = (256.0f * C - Cg - S) * (1.0f / 327424.0f);
    }
}

extern "C" void kernel_launch(void* const* d_in, const int* in_sizes, int n_in,
                              void* d_out, int out_size, void* d_ws, size_t ws_size,
                              hipStream_t stream) {
    const float* sg     = (const float*)d_in[0];   // out_student_global [256, D]
    const float* sl     = (const float*)d_in[1];   // out_student_local  [1024, D]
    const float* tch    = (const float*)d_in[2];   // out_teacher        [256, D]
    const float* center = (const float*)d_in[3];   // [1, D]
    const float* tempS  = (const float*)d_in[4];
    const float* tempT  = (const float*)d_in[5];
    // d_in[6] = cent_rate_m (unused by the reference output)

    float* ws = (float*)d_ws;
    float*  Sxs     = ws;                                         // D floats
    float2* stats   = (float2*)(ws + D);                          // NS*CT float2
    float4* tup     = (float4*)(ws + D + NS * CT * 2);            // NT*KC_SPLIT float4
    float*  partial = ws + D + NS * CT * 2 + NT * KC_SPLIT * 4;   // RG*D floats

    const size_t needed = (size_t)(D + NS * CT * 2 + NT * KC_SPLIT * 4 + RG * D) * sizeof(float);
    const int use_atomic = (ws_size < needed) ? 1 : 0;

    if (use_atomic)
        hipMemsetAsync(Sxs, 0, D * sizeof(float), stream);
    kA<<<dim3(CT, RG), 256, 0, stream>>>(sg, sl, tempS, Sxs, partial, stats, use_atomic);
    if (!use_atomic)
        kB<<<D / 256, 256, 0, stream>>>(partial, Sxs);
    kC<<<NT * KC_SPLIT, 256, 0, stream>>>(tch, sg, center, Sxs, tempS, tempT, tup);
    kD<<<1, 256, 0, stream>>>(stats, tup, (float*)d_out);
}